// Round 1
// baseline (366.171 us; speedup 1.0000x reference)
//
#include <hip/hip_runtime.h>

#define N_TOK  16384   // B*H*W = 16*32*32
#define KCODES 2048
#define CDIM   128
#define BDIM   16
#define HWDIM  1024    // H*W
#define BM     64
#define BN     64
#define TPB    256
#define BPAD   133     // Bs leading-dim pad: 133*4 B -> bank step 5 -> 2-way (free)

// ---------------- kernel 1: ||w||^2 per code (wave per code) ----------------
__global__ __launch_bounds__(256) void wsq_kernel(const float* __restrict__ cb,
                                                  float* __restrict__ wsq) {
    int code = (blockIdx.x * blockDim.x + threadIdx.x) >> 6;  // wave id
    int lane = threadIdx.x & 63;
    if (code >= KCODES) return;
    const float2* row = (const float2*)(cb + (size_t)code * CDIM);
    float2 a = row[lane];                       // 64 lanes x 2 floats = 128
    float s = a.x * a.x + a.y * a.y;
    #pragma unroll
    for (int off = 32; off > 0; off >>= 1) s += __shfl_down(s, off, 64);
    if (lane == 0) wsq[code] = s;
}

// ------- kernel 2: fused GEMM + argmin + one-hot write + idx store ----------
__global__ __launch_bounds__(TPB) void argmin_kernel(const float* __restrict__ x,
                                                     const float* __restrict__ cb,
                                                     const float* __restrict__ wsq,
                                                     float* __restrict__ enc,
                                                     int* __restrict__ out_idx) {
    __shared__ float As[CDIM][BM];        // 32 KB, transposed: As[c][m]
    __shared__ float Bs[BN][BPAD];        // ~34 KB, row-major codes
    __shared__ float wsqs[BN];
    __shared__ float redv[BM][17];
    __shared__ int   redi[BM][17];
    __shared__ int   rowidx[BM];

    const int tid = threadIdx.x;
    const int n0  = blockIdx.x * BM;      // 64 rows, never crosses a batch (1024%64==0)
    const int b   = n0 >> 10;
    const int hw0 = n0 & 1023;

    // ---- stage A (once): x_flat[n][c] = x[(b*C+c)*1024 + hw]  (c-major -> no transpose)
    {
        int m4 = (tid & 15) << 2;         // 0..60
        int c0 = tid >> 4;                // 0..15
        #pragma unroll
        for (int i = 0; i < 8; i++) {
            int c = c0 + 16 * i;
            float4 v = *(const float4*)(x + (((size_t)(b * CDIM + c)) << 10) + hw0 + m4);
            *(float4*)(&As[c][m4]) = v;
        }
    }

    const int tx = tid & 15;              // col group (4 codes)
    const int ty = tid >> 4;              // row group (4 rows)

    float rminv[4];
    int   rmini[4];
    #pragma unroll
    for (int j = 0; j < 4; j++) { rminv[j] = 3.0e38f; rmini[j] = 0; }

    for (int t = 0; t < KCODES / BN; ++t) {
        const int k0 = t * BN;
        __syncthreads();  // Bs from previous tile fully consumed (also covers As staging on t==0)

        // ---- stage B tile: Bs[k][c], coalesced float4 reads, b32 writes (pad 133)
        {
            int c4 = (tid & 31) << 2;     // 0..124
            int kk = tid >> 5;            // 0..7
            #pragma unroll
            for (int i = 0; i < 8; i++) {
                int k = kk + 8 * i;
                float4 v = *(const float4*)(cb + (size_t)(k0 + k) * CDIM + c4);
                Bs[k][c4 + 0] = v.x; Bs[k][c4 + 1] = v.y;
                Bs[k][c4 + 2] = v.z; Bs[k][c4 + 3] = v.w;
            }
            if (tid < BN) wsqs[tid] = wsq[k0 + tid];
        }
        __syncthreads();

        // ---- 4x4 micro-tile fp32 GEMM over full C=128
        float acc[4][4] = {{0.f}};
        #pragma unroll 8
        for (int c = 0; c < CDIM; ++c) {
            float4 av = *(const float4*)(&As[c][ty << 2]);
            float b0 = Bs[(tx << 2) + 0][c];
            float b1 = Bs[(tx << 2) + 1][c];
            float b2 = Bs[(tx << 2) + 2][c];
            float b3 = Bs[(tx << 2) + 3][c];
            const float* a = (const float*)&av;
            #pragma unroll
            for (int j = 0; j < 4; j++) {
                acc[j][0] = fmaf(a[j], b0, acc[j][0]);
                acc[j][1] = fmaf(a[j], b1, acc[j][1]);
                acc[j][2] = fmaf(a[j], b2, acc[j][2]);
                acc[j][3] = fmaf(a[j], b3, acc[j][3]);
            }
        }

        // ---- running argmin (k ascending within thread -> first-index tie-break)
        #pragma unroll
        for (int i = 0; i < 4; i++) {
            int   k = k0 + (tx << 2) + i;
            float w = wsqs[(tx << 2) + i];
            #pragma unroll
            for (int j = 0; j < 4; j++) {
                float s = fmaf(-2.0f, acc[j][i], w);   // ||x||^2 const per row: argmin-invariant
                if (s < rminv[j]) { rminv[j] = s; rmini[j] = k; }
            }
        }
    }

    // ---- reduce across the 16 col-groups per row
    __syncthreads();
    #pragma unroll
    for (int j = 0; j < 4; j++) {
        redv[(ty << 2) + j][tx] = rminv[j];
        redi[(ty << 2) + j][tx] = rmini[j];
    }
    __syncthreads();
    if (tid < BM) {
        float bv = redv[tid][0];
        int   bi = redi[tid][0];
        #pragma unroll
        for (int i = 1; i < 16; i++) {
            float v = redv[tid][i];
            int   ii = redi[tid][i];
            if (v < bv || (v == bv && ii < bi)) { bv = v; bi = ii; }
        }
        rowidx[tid] = bi;
        out_idx[n0 + tid] = bi;
    }
    __syncthreads();

    // ---- write one-hot rows (64 x 2048 floats), coalesced float4
    for (int i = tid; i < BM * (KCODES / 4); i += TPB) {
        int row = i >> 9;                 // /512
        int c4  = (i & 511) << 2;
        int idx = rowidx[row];
        float4 v = {0.f, 0.f, 0.f, 0.f};
        if ((idx >> 2) == (c4 >> 2)) ((float*)&v)[idx & 3] = 1.0f;
        *(float4*)(enc + (size_t)(n0 + row) * KCODES + c4) = v;
    }
}

// ---------- kernel 3: quantized = codebook[idx], NCHW coalesced float4 ------
__global__ __launch_bounds__(256) void quant_kernel(const float* __restrict__ cb,
                                                    const int* __restrict__ idxp,
                                                    float* __restrict__ q) {
    int t = blockIdx.x * blockDim.x + threadIdx.x;   // 0..524287 (float4 units)
    int hw4 = (t & 255) << 2;
    int c   = (t >> 8) & 127;
    int b   = t >> 15;
    int4 iv = *(const int4*)(idxp + ((b << 10) + hw4));
    float4 v;
    v.x = cb[(size_t)iv.x * CDIM + c];
    v.y = cb[(size_t)iv.y * CDIM + c];
    v.z = cb[(size_t)iv.z * CDIM + c];
    v.w = cb[(size_t)iv.w * CDIM + c];
    *(float4*)(q + ((size_t)t << 2)) = v;
}

extern "C" void kernel_launch(void* const* d_in, const int* in_sizes, int n_in,
                              void* d_out, int out_size, void* d_ws, size_t ws_size,
                              hipStream_t stream) {
    const float* x  = (const float*)d_in[0];   // [16,128,32,32] f32
    const float* cb = (const float*)d_in[1];   // [2048,128] f32
    float* out = (float*)d_out;                // encodings [N,K] then quantized [B,C,H,W]

    int*   idxp = (int*)d_ws;                  // N ints
    float* wsqp = (float*)d_ws + N_TOK;        // K floats

    wsq_kernel<<<KCODES / 4, 256, 0, stream>>>(cb, wsqp);
    argmin_kernel<<<N_TOK / BM, TPB, 0, stream>>>(x, cb, wsqp, out, idxp);
    quant_kernel<<<(N_TOK * CDIM / 4) / 256, 256, 0, stream>>>(
        cb, idxp, out + (size_t)N_TOK * KCODES);
}

// Round 2
// 346.404 us; speedup vs baseline: 1.0571x; 1.0571x over previous
//
#include <hip/hip_runtime.h>

#define N_TOK  16384   // B*H*W = 16*32*32
#define KCODES 2048
#define CDIM   128
#define BM     64
#define TPB    256
#define BN_S   256                  // codes per stage
#define NSTAGE (KCODES / BN_S)      // 8
#define CHALF  64                   // dims staged per pass
#define BSPAD  68                   // Bs row stride: 68%32==4 -> conflict-free b128 compute reads

// acc.x += b.x * a.x ; acc.y += b.x * a.y   (splat LOW half of b)
__device__ __forceinline__ void pk_fma_lo(float2& acc, const float2& b, const float2& a) {
    asm("v_pk_fma_f32 %0, %1, %2, %0 op_sel:[0,0,0] op_sel_hi:[0,1,1]"
        : "+v"(acc) : "v"(b), "v"(a));
}
// acc.x += b.y * a.x ; acc.y += b.y * a.y   (splat HIGH half of b)
__device__ __forceinline__ void pk_fma_hi(float2& acc, const float2& b, const float2& a) {
    asm("v_pk_fma_f32 %0, %1, %2, %0 op_sel:[1,0,0] op_sel_hi:[1,1,1]"
        : "+v"(acc) : "v"(b), "v"(a));
}

// ---------------- kernel 1: ||w||^2 per code (wave per code) ----------------
__global__ __launch_bounds__(256) void wsq_kernel(const float* __restrict__ cb,
                                                  float* __restrict__ wsq) {
    int code = (blockIdx.x * blockDim.x + threadIdx.x) >> 6;
    int lane = threadIdx.x & 63;
    if (code >= KCODES) return;
    const float2* row = (const float2*)(cb + (size_t)code * CDIM);
    float2 a = row[lane];
    float s = a.x * a.x + a.y * a.y;
    #pragma unroll
    for (int off = 32; off > 0; off >>= 1) s += __shfl_down(s, off, 64);
    if (lane == 0) wsq[code] = s;
}

// ------- kernel 2: fused GEMM + argmin + one-hot write + idx store ----------
__global__ __launch_bounds__(TPB, 1) void argmin_kernel(const float* __restrict__ x,
                                                        const float* __restrict__ cbp,
                                                        const float* __restrict__ wsq,
                                                        float* __restrict__ enc,
                                                        int* __restrict__ out_idx) {
    __shared__ float As[CDIM][BM];          // 32 KB, As[c][m] (x is c-major: no transpose)
    __shared__ float Bs[BN_S][BSPAD];       // 68 KB, Bs[k_local][c_local]
    __shared__ float redv[BM][33];
    __shared__ int   redi[BM][33];
    __shared__ int   rowidx[BM];

    const int tid = threadIdx.x;
    const int n0  = blockIdx.x * BM;        // 1024 % 64 == 0: never crosses a batch
    const int b   = n0 >> 10;
    const int hw0 = n0 & 1023;

    // ---- stage A once: As[c][m] from x[(b*C+c)*1024 + hw] (coalesced float4)
    {
        int m4 = (tid & 15) << 2;
        int c0 = tid >> 4;
        #pragma unroll
        for (int i = 0; i < 8; i++) {
            int c = c0 + 16 * i;
            float4 v = *(const float4*)(x + (((size_t)(b * CDIM + c)) << 10) + hw0 + m4);
            *(float4*)(&As[c][m4]) = v;
        }
    }

    const int tx   = tid & 31;              // 32 code-groups
    const int ty   = tid >> 5;              // 8 row-groups
    const int row0 = ty << 3;               // 8 rows per thread

    float rminv[8]; int rmini[8];
    #pragma unroll
    for (int r = 0; r < 8; r++) { rminv[r] = 3.0e38f; rmini[r] = 0; }

    for (int s = 0; s < NSTAGE; ++s) {
        const int kb = s * BN_S;
        float wq[8];
        #pragma unroll
        for (int j = 0; j < 8; j++) wq[j] = wsq[kb + tx + 32 * j];

        float2 acc2[4][8];                  // [row-pair][code], 64 VGPRs
        #pragma unroll
        for (int rp = 0; rp < 4; rp++)
            #pragma unroll
            for (int j = 0; j < 8; j++) acc2[rp][j] = make_float2(0.f, 0.f);

        for (int pass = 0; pass < 2; ++pass) {
            const int cb0 = pass * CHALF;
            __syncthreads();                // prev consumers of Bs done (covers As on s==0)
            // ---- stage Bs: 256 codes x 64 dims, coalesced float4
            #pragma unroll
            for (int i = 0; i < 16; i++) {
                int g  = i * TPB + tid;
                int kp = g >> 4;
                int cq = (g & 15) << 2;
                float4 v = *(const float4*)(cbp + (size_t)(kb + kp) * CDIM + cb0 + cq);
                *(float4*)(&Bs[kp][cq]) = v;
            }
            __syncthreads();

            // ---- compute: 16 groups of 4 dims
            #pragma unroll 4
            for (int cg = 0; cg < 16; ++cg) {
                const int cc = cg << 2;
                float4 bb[8];
                #pragma unroll
                for (int j = 0; j < 8; j++)
                    bb[j] = *(const float4*)(&Bs[tx + 32 * j][cc]);   // conflict-free b128
                #pragma unroll
                for (int cp = 0; cp < 4; cp++) {
                    const float* ar = &As[cb0 + cc + cp][row0];
                    float4 a0 = *(const float4*)(ar);
                    float4 a1 = *(const float4*)(ar + 4);             // 2-addr broadcast reads
                    float2 aa0 = make_float2(a0.x, a0.y);
                    float2 aa1 = make_float2(a0.z, a0.w);
                    float2 aa2 = make_float2(a1.x, a1.y);
                    float2 aa3 = make_float2(a1.z, a1.w);
                    #pragma unroll
                    for (int j = 0; j < 8; j++) {
                        float2 bp = (cp < 2) ? make_float2(bb[j].x, bb[j].y)
                                             : make_float2(bb[j].z, bb[j].w);
                        if ((cp & 1) == 0) {
                            pk_fma_lo(acc2[0][j], bp, aa0);
                            pk_fma_lo(acc2[1][j], bp, aa1);
                            pk_fma_lo(acc2[2][j], bp, aa2);
                            pk_fma_lo(acc2[3][j], bp, aa3);
                        } else {
                            pk_fma_hi(acc2[0][j], bp, aa0);
                            pk_fma_hi(acc2[1][j], bp, aa1);
                            pk_fma_hi(acc2[2][j], bp, aa2);
                            pk_fma_hi(acc2[3][j], bp, aa3);
                        }
                    }
                }
            }
        }

        // ---- per-stage argmin update (k ascending: j asc within asc stages)
        #pragma unroll
        for (int j = 0; j < 8; j++) {
            int   k = kb + tx + 32 * j;
            float w = wq[j];
            #pragma unroll
            for (int rp = 0; rp < 4; rp++) {
                float s0 = fmaf(-2.f, acc2[rp][j].x, w);   // ||x||^2 omitted: argmin-invariant
                float s1 = fmaf(-2.f, acc2[rp][j].y, w);
                int r0 = rp * 2, r1 = rp * 2 + 1;
                if (s0 < rminv[r0]) { rminv[r0] = s0; rmini[r0] = k; }
                if (s1 < rminv[r1]) { rminv[r1] = s1; rmini[r1] = k; }
            }
        }
    }

    // ---- reduce across the 32 tx-groups per row
    __syncthreads();
    #pragma unroll
    for (int r = 0; r < 8; r++) {
        redv[row0 + r][tx] = rminv[r];
        redi[row0 + r][tx] = rmini[r];
    }
    __syncthreads();
    if (tid < BM) {
        float bv = redv[tid][0];
        int   bi = redi[tid][0];
        #pragma unroll
        for (int i = 1; i < 32; i++) {
            float v = redv[tid][i];
            int   ii = redi[tid][i];
            if (v < bv || (v == bv && ii < bi)) { bv = v; bi = ii; }
        }
        rowidx[tid] = bi;
        out_idx[n0 + tid] = bi;
    }
    __syncthreads();

    // ---- one-hot rows (64 x 2048 floats), coalesced float4
    for (int i = tid; i < BM * (KCODES / 4); i += TPB) {
        int row = i >> 9;
        int c4  = (i & 511) << 2;
        int idx = rowidx[row];
        float4 v = {0.f, 0.f, 0.f, 0.f};
        if ((idx >> 2) == (c4 >> 2)) ((float*)&v)[idx & 3] = 1.0f;
        *(float4*)(enc + (size_t)(n0 + row) * KCODES + c4) = v;
    }
}

// ---------- kernel 3: quantized = codebook[idx], NCHW coalesced float4 ------
__global__ __launch_bounds__(256) void quant_kernel(const float* __restrict__ cb,
                                                    const int* __restrict__ idxp,
                                                    float* __restrict__ q) {
    int t = blockIdx.x * blockDim.x + threadIdx.x;
    int hw4 = (t & 255) << 2;
    int c   = (t >> 8) & 127;
    int b   = t >> 15;
    int4 iv = *(const int4*)(idxp + ((b << 10) + hw4));
    float4 v;
    v.x = cb[(size_t)iv.x * CDIM + c];
    v.y = cb[(size_t)iv.y * CDIM + c];
    v.z = cb[(size_t)iv.z * CDIM + c];
    v.w = cb[(size_t)iv.w * CDIM + c];
    *(float4*)(q + ((size_t)t << 2)) = v;
}

extern "C" void kernel_launch(void* const* d_in, const int* in_sizes, int n_in,
                              void* d_out, int out_size, void* d_ws, size_t ws_size,
                              hipStream_t stream) {
    const float* x  = (const float*)d_in[0];   // [16,128,32,32] f32
    const float* cb = (const float*)d_in[1];   // [2048,128] f32
    float* out = (float*)d_out;                // encodings [N,K] then quantized [B,C,H,W]

    int*   idxp = (int*)d_ws;                  // N ints
    float* wsqp = (float*)d_ws + N_TOK;        // K floats

    wsq_kernel<<<KCODES / 4, 256, 0, stream>>>(cb, wsqp);
    argmin_kernel<<<N_TOK / BM, TPB, 0, stream>>>(x, cb, wsqp, out, idxp);
    quant_kernel<<<(N_TOK * CDIM / 4) / 256, 256, 0, stream>>>(
        cb, idxp, out + (size_t)N_TOK * KCODES);
}

// Round 3
// 270.848 us; speedup vs baseline: 1.3519x; 1.2790x over previous
//
#include <hip/hip_runtime.h>
#include <hip/hip_bf16.h>

#define N_TOK  16384   // B*H*W
#define KCODES 2048
#define CDIM   128
#define BM     64
#define TPB    256
#define CHUNK  256
#define NCHUNK (KCODES / CHUNK)
#define CAP    48
#define DELTA  8.0f     // >= 2x worst-case bf16-rounding bound on d2 (~4)
#define ASTR   68       // As row stride (floats): 16B-aligned, breaks 64-stride banks
#define BSTR   136      // Bs row stride (shorts) = 272 B: (r+q)%8 even -> conflict-free b128

typedef __attribute__((ext_vector_type(8))) short bhalf8;
typedef __attribute__((ext_vector_type(4))) float facc4;

// ---------------- kernel 1: ||w||^2 per code (wave per code) ----------------
__global__ __launch_bounds__(256) void wsq_kernel(const float* __restrict__ cb,
                                                  float* __restrict__ wsq) {
    int code = (blockIdx.x * blockDim.x + threadIdx.x) >> 6;
    int lane = threadIdx.x & 63;
    if (code >= KCODES) return;
    const float2* row = (const float2*)(cb + (size_t)code * CDIM);
    float2 a = row[lane];
    float s = a.x * a.x + a.y * a.y;
    #pragma unroll
    for (int off = 32; off > 0; off >>= 1) s += __shfl_down(s, off, 64);
    if (lane == 0) wsq[code] = s;
}

// ---- kernel 2: bf16-MFMA argmin (2 sweeps) + exact fp32 rescue + one-hot ----
__global__ __launch_bounds__(TPB, 1) void argmin_kernel(const float* __restrict__ x,
                                                        const float* __restrict__ cb,
                                                        const float* __restrict__ wsqg,
                                                        float* __restrict__ enc,
                                                        int* __restrict__ out_idx) {
    __shared__ float          As[CDIM][ASTR];     // 34.8 KB fp32 (exact x, c-major)
    __shared__ unsigned short Bs[CHUNK][BSTR];    // 69.6 KB bf16 codes
    __shared__ float wsqs[KCODES];                // 8 KB
    __shared__ float redvw[4][BM];
    __shared__ float rowthr[BM];
    __shared__ int   cnt[BM];
    __shared__ int   candk[BM][CAP];
    __shared__ int   rowidx[BM];

    const int tid  = threadIdx.x;
    const int lane = tid & 63;
    const int w    = tid >> 6;
    const int q    = lane >> 4;
    const int r    = lane & 15;
    const int n0   = blockIdx.x * BM;             // 1024 % 64 == 0: single batch
    const int b    = n0 >> 10;
    const int hw0  = n0 & 1023;

    // ---- stage As fp32 (coalesced float4 over hw), wsq -> LDS, init cnt
    {
        int m4 = (tid & 15) << 2;
        int c0 = tid >> 4;
        #pragma unroll
        for (int i = 0; i < 8; i++) {
            int c = c0 + 16 * i;
            float4 v = *(const float4*)(x + (((size_t)(b * CDIM + c)) << 10) + hw0 + m4);
            *(float4*)(&As[c][m4]) = v;
        }
    }
    #pragma unroll
    for (int i = 0; i < KCODES / TPB; i++) wsqs[i * TPB + tid] = wsqg[i * TPB + tid];
    if (tid < BM) cnt[tid] = 0;
    __syncthreads();

    // ---- build A-frags in registers ONCE (16 frags = 64 VGPR, zero loop LDS-A traffic)
    // A operand: A[m = lane&15][k = q*8 + j]  (verified layout)
    bhalf8 af[4][4];
    #pragma unroll
    for (int rt = 0; rt < 4; rt++) {
        int m = rt * 16 + r;
        #pragma unroll
        for (int kf = 0; kf < 4; kf++) {
            union { unsigned u[4]; bhalf8 v; } fu;
            #pragma unroll
            for (int p = 0; p < 4; p++) {
                int k = kf * 32 + q * 8 + 2 * p;
                __hip_bfloat162 h = __float22bfloat162_rn(make_float2(As[k][m], As[k + 1][m]));
                fu.u[p] = *(unsigned*)&h;
            }
            af[rt][kf] = fu.v;
        }
    }

    // ---- B staging: global fp32 -> bf16 -> LDS (coalesced dwordx4 x2 per thread-iter)
    auto stage_B = [&](int kb) {
        #pragma unroll
        for (int i = 0; i < 16; i++) {
            int g  = i * TPB + tid;
            int kp = g >> 4;
            int cs = (g & 15) << 3;
            const float4* src = (const float4*)(cb + (size_t)(kb + kp) * CDIM + cs);
            float4 a0 = src[0], a1 = src[1];
            union { unsigned u[4]; bhalf8 v; } fu;
            __hip_bfloat162 h0 = __float22bfloat162_rn(make_float2(a0.x, a0.y));
            __hip_bfloat162 h1 = __float22bfloat162_rn(make_float2(a0.z, a0.w));
            __hip_bfloat162 h2 = __float22bfloat162_rn(make_float2(a1.x, a1.y));
            __hip_bfloat162 h3 = __float22bfloat162_rn(make_float2(a1.z, a1.w));
            fu.u[0] = *(unsigned*)&h0; fu.u[1] = *(unsigned*)&h1;
            fu.u[2] = *(unsigned*)&h2; fu.u[3] = *(unsigned*)&h3;
            *(bhalf8*)(&Bs[kp][cs]) = fu.v;
        }
    };

    // =================== SWEEP 1: per-row approx min (value only) ===================
    float rmin[16];
    #pragma unroll
    for (int t = 0; t < 16; t++) rmin[t] = 3.0e38f;

    for (int ch = 0; ch < NCHUNK; ch++) {
        const int kb = ch * CHUNK;
        __syncthreads();
        stage_B(kb);
        __syncthreads();
        #pragma unroll
        for (int ct = 0; ct < 4; ct++) {
            const int nb = w * 64 + ct * 16;      // wave's code quarter
            bhalf8 bf[4];
            #pragma unroll
            for (int kf = 0; kf < 4; kf++)
                bf[kf] = *(const bhalf8*)(&Bs[nb + r][kf * 32 + q * 8]);
            facc4 acc[4];
            #pragma unroll
            for (int rt = 0; rt < 4; rt++) acc[rt] = (facc4){0.f, 0.f, 0.f, 0.f};
            #pragma unroll
            for (int kf = 0; kf < 4; kf++)
                #pragma unroll
                for (int rt = 0; rt < 4; rt++)
                    acc[rt] = __builtin_amdgcn_mfma_f32_16x16x32_bf16(af[rt][kf], bf[kf], acc[rt], 0, 0, 0);
            float wv = wsqs[kb + nb + r];
            #pragma unroll
            for (int rt = 0; rt < 4; rt++)
                #pragma unroll
                for (int i = 0; i < 4; i++)
                    rmin[rt * 4 + i] = fminf(rmin[rt * 4 + i], fmaf(-2.f, acc[rt][i], wv));
        }
    }

    // ---- reduce min over the 16 col-lanes (butterfly), then over 4 waves
    #pragma unroll
    for (int t = 0; t < 16; t++) {
        float v = rmin[t];
        v = fminf(v, __shfl_xor(v, 1, 64));
        v = fminf(v, __shfl_xor(v, 2, 64));
        v = fminf(v, __shfl_xor(v, 4, 64));
        v = fminf(v, __shfl_xor(v, 8, 64));
        if (r == 0) redvw[w][(t >> 2) * 16 + q * 4 + (t & 3)] = v;
    }
    __syncthreads();
    if (tid < BM)
        rowthr[tid] = fminf(fminf(redvw[0][tid], redvw[1][tid]),
                            fminf(redvw[2][tid], redvw[3][tid])) + DELTA;
    __syncthreads();

    float thr[16];
    #pragma unroll
    for (int t = 0; t < 16; t++) thr[t] = rowthr[(t >> 2) * 16 + q * 4 + (t & 3)];

    // =================== SWEEP 2: recompute (bitwise-identical), collect candidates ===
    for (int ch = 0; ch < NCHUNK; ch++) {
        const int kb = ch * CHUNK;
        __syncthreads();
        stage_B(kb);
        __syncthreads();
        #pragma unroll
        for (int ct = 0; ct < 4; ct++) {
            const int nb = w * 64 + ct * 16;
            bhalf8 bf[4];
            #pragma unroll
            for (int kf = 0; kf < 4; kf++)
                bf[kf] = *(const bhalf8*)(&Bs[nb + r][kf * 32 + q * 8]);
            facc4 acc[4];
            #pragma unroll
            for (int rt = 0; rt < 4; rt++) acc[rt] = (facc4){0.f, 0.f, 0.f, 0.f};
            #pragma unroll
            for (int kf = 0; kf < 4; kf++)
                #pragma unroll
                for (int rt = 0; rt < 4; rt++)
                    acc[rt] = __builtin_amdgcn_mfma_f32_16x16x32_bf16(af[rt][kf], bf[kf], acc[rt], 0, 0, 0);
            float wv = wsqs[kb + nb + r];
            #pragma unroll
            for (int rt = 0; rt < 4; rt++)
                #pragma unroll
                for (int i = 0; i < 4; i++) {
                    float d = fmaf(-2.f, acc[rt][i], wv);
                    if (d <= thr[rt * 4 + i]) {
                        int row = rt * 16 + q * 4 + i;
                        int p = atomicAdd(&cnt[row], 1);
                        if (p < CAP) candk[row][p] = kb + nb + r;
                    }
                }
        }
    }
    __syncthreads();

    // =================== SWEEP 3: exact fp32 re-score of candidates ===================
    // wave w handles rows [16w, 16w+16); wave-cooperative dot (lane j: dims j, j+64)
    for (int m = 16 * w; m < 16 * w + 16; m++) {
        int c = min(cnt[m], CAP);
        float bv = 3.0e38f; int bk = 0x7fffffff;
        for (int t = 0; t < c; t++) {
            int k = candk[m][t];
            float x0 = As[lane][m], x1 = As[lane + 64][m];
            float c0 = cb[(size_t)k * CDIM + lane];
            float c1 = cb[(size_t)k * CDIM + 64 + lane];
            float s = x0 * c0 + x1 * c1;
            #pragma unroll
            for (int off = 1; off <= 32; off <<= 1) s += __shfl_xor(s, off, 64);
            float d = fmaf(-2.f, s, wsqs[k]);
            if (d < bv || (d == bv && k < bk)) { bv = d; bk = k; }
        }
        if (lane == 0) { rowidx[m] = bk; out_idx[n0 + m] = bk; }
    }
    __syncthreads();

    // ---- one-hot rows (64 x 2048 floats), coalesced float4
    for (int i = tid; i < BM * (KCODES / 4); i += TPB) {
        int row = i >> 9;
        int c4  = (i & 511) << 2;
        int idx = rowidx[row];
        float4 v = {0.f, 0.f, 0.f, 0.f};
        if ((idx >> 2) == (c4 >> 2)) ((float*)&v)[idx & 3] = 1.0f;
        *(float4*)(enc + (size_t)(n0 + row) * KCODES + c4) = v;
    }
}

// ---------- kernel 3: quantized = codebook[idx], NCHW coalesced float4 ------
__global__ __launch_bounds__(256) void quant_kernel(const float* __restrict__ cb,
                                                    const int* __restrict__ idxp,
                                                    float* __restrict__ q) {
    int t = blockIdx.x * blockDim.x + threadIdx.x;
    int hw4 = (t & 255) << 2;
    int c   = (t >> 8) & 127;
    int b   = t >> 15;
    int4 iv = *(const int4*)(idxp + ((b << 10) + hw4));
    float4 v;
    v.x = cb[(size_t)iv.x * CDIM + c];
    v.y = cb[(size_t)iv.y * CDIM + c];
    v.z = cb[(size_t)iv.z * CDIM + c];
    v.w = cb[(size_t)iv.w * CDIM + c];
    *(float4*)(q + ((size_t)t << 2)) = v;
}

extern "C" void kernel_launch(void* const* d_in, const int* in_sizes, int n_in,
                              void* d_out, int out_size, void* d_ws, size_t ws_size,
                              hipStream_t stream) {
    const float* x  = (const float*)d_in[0];   // [16,128,32,32] f32
    const float* cb = (const float*)d_in[1];   // [2048,128] f32
    float* out = (float*)d_out;                // encodings [N,K] then quantized [B,C,H,W]

    int*   idxp = (int*)d_ws;                  // N ints
    float* wsqp = (float*)d_ws + N_TOK;        // K floats

    wsq_kernel<<<KCODES / 4, 256, 0, stream>>>(cb, wsqp);
    argmin_kernel<<<N_TOK / BM, TPB, 0, stream>>>(x, cb, wsqp, out, idxp);
    quant_kernel<<<(N_TOK * CDIM / 4) / 256, 256, 0, stream>>>(
        cb, idxp, out + (size_t)N_TOK * KCODES);
}

// Round 4
// 203.033 us; speedup vs baseline: 1.8035x; 1.3340x over previous
//
#include <hip/hip_runtime.h>
#include <hip/hip_bf16.h>

#define N_TOK  16384   // B*H*W
#define KCODES 2048
#define CDIM   128
#define BM     64
#define TPB    512     // 8 waves: each wave owns 256 codes
#define NTILE  16      // 16-code tiles per wave per sweep
#define CAP    40
#define DELTA  5.0f    // error bound on d2a ~1.05; need >= 2x; 5 is ~5x safe
#define ASTR   68

typedef __attribute__((ext_vector_type(8))) short bhalf8;
typedef __attribute__((ext_vector_type(4))) float facc4;

// ---- prep: codebook fp32 -> bf16 in MFMA-frag-tiled layout, + ||w||^2 ----
// tiled layout: element (16B) index = T*256 + kf*64 + (q*16 + r)
//   holds code (T*16+r), dims [kf*32 + q*8, +8)  == B-frag for (tile T, kf)
__global__ __launch_bounds__(256) void prep_kernel(const float* __restrict__ cb,
                                                   bhalf8* __restrict__ cbt,
                                                   float* __restrict__ wsq) {
    const int T   = blockIdx.x;        // tile of 16 codes
    const int tid = threadIdx.x;
    const int r   = tid >> 4;          // code within tile (0..15)
    const int g   = tid & 15;          // dim-group of 8 (0..15)
    const float4* src = (const float4*)(cb + ((size_t)(T * 16 + r)) * CDIM + g * 8);
    float4 a0 = src[0], a1 = src[1];   // coalesced: 16 threads cover one 512B row

    // ||w||^2: partial over 8 dims, reduce over g (lane bits 0..3)
    float s = a0.x*a0.x + a0.y*a0.y + a0.z*a0.z + a0.w*a0.w
            + a1.x*a1.x + a1.y*a1.y + a1.z*a1.z + a1.w*a1.w;
    s += __shfl_xor(s, 1, 64);
    s += __shfl_xor(s, 2, 64);
    s += __shfl_xor(s, 4, 64);
    s += __shfl_xor(s, 8, 64);
    if (g == 0) wsq[T * 16 + r] = s;

    // convert + tiled store
    union { unsigned u[4]; bhalf8 v; } fu;
    __hip_bfloat162 h0 = __float22bfloat162_rn(make_float2(a0.x, a0.y));
    __hip_bfloat162 h1 = __float22bfloat162_rn(make_float2(a0.z, a0.w));
    __hip_bfloat162 h2 = __float22bfloat162_rn(make_float2(a1.x, a1.y));
    __hip_bfloat162 h3 = __float22bfloat162_rn(make_float2(a1.z, a1.w));
    fu.u[0] = *(unsigned*)&h0; fu.u[1] = *(unsigned*)&h1;
    fu.u[2] = *(unsigned*)&h2; fu.u[3] = *(unsigned*)&h3;
    const int kf = g >> 2, q = g & 3;
    cbt[(size_t)T * 256 + kf * 64 + q * 16 + r] = fu.v;
}

// ---- main: barrier-free MFMA sweeps from L2 + rescue + one-hot + quant ----
__global__ __launch_bounds__(TPB, 2) void argmin_kernel(const float* __restrict__ x,
                                                        const float* __restrict__ cb,
                                                        const bhalf8* __restrict__ cbt,
                                                        const float* __restrict__ wsqg,
                                                        float* __restrict__ enc,
                                                        float* __restrict__ quant) {
    __shared__ float As[CDIM][ASTR];     // 34.8 KB exact fp32 x, c-major
    __shared__ float wsqs[KCODES];       // 8 KB
    __shared__ float redvw[8][BM];
    __shared__ float rowthr[BM];
    __shared__ int   cnt[BM];
    __shared__ int   candk[BM][CAP];
    __shared__ int   rowidx[BM];

    const int tid  = threadIdx.x;
    const int lane = tid & 63;
    const int w    = tid >> 6;           // 8 waves
    const int q    = lane >> 4;
    const int r    = lane & 15;
    const int n0   = blockIdx.x * BM;    // 1024 % 64 == 0: single batch
    const int b    = n0 >> 10;
    const int hw0  = n0 & 1023;
    const int cbase = w * 256;           // wave's code range [cbase, cbase+256)
    const size_t zb = (size_t)n0 * KCODES;
    const float4 z4 = {0.f, 0.f, 0.f, 0.f};

    // ---- stage As (coalesced float4 over hw), wsqs, init cnt
    {
        int m4 = (tid & 15) << 2;
        int c0 = tid >> 4;               // 0..31
        #pragma unroll
        for (int i = 0; i < 4; i++) {
            int c = c0 + 32 * i;
            float4 v = *(const float4*)(x + (((size_t)(b * CDIM + c)) << 10) + hw0 + m4);
            *(float4*)(&As[c][m4]) = v;
        }
    }
    #pragma unroll
    for (int i = 0; i < KCODES / TPB; i++) wsqs[i * TPB + tid] = wsqg[i * TPB + tid];
    if (tid < BM) cnt[tid] = 0;
    __syncthreads();

    // ---- A-frags in registers once: A[m = lane&15][k = q*8+j] (R3-verified)
    bhalf8 af[4][4];
    #pragma unroll
    for (int rt = 0; rt < 4; rt++) {
        int m = rt * 16 + r;
        #pragma unroll
        for (int kf = 0; kf < 4; kf++) {
            union { unsigned u[4]; bhalf8 v; } fu;
            #pragma unroll
            for (int p = 0; p < 4; p++) {
                int k = kf * 32 + q * 8 + 2 * p;
                __hip_bfloat162 h = __float22bfloat162_rn(make_float2(As[k][m], As[k + 1][m]));
                fu.u[p] = *(unsigned*)&h;
            }
            af[rt][kf] = fu.v;
        }
    }

    // =============== SWEEP 1: approx min per row (no barriers) ===============
    float rmin[16];
    #pragma unroll
    for (int t = 0; t < 16; t++) rmin[t] = 3.0e38f;

    {
        bhalf8 bf[4];
        #pragma unroll
        for (int kf = 0; kf < 4; kf++)
            bf[kf] = cbt[((size_t)(cbase >> 4)) * 256 + kf * 64 + lane];
        #pragma unroll
        for (int t = 0; t < NTILE; t++) {
            bhalf8 bn[4];
            if (t + 1 < NTILE) {
                size_t tb = ((size_t)((cbase >> 4) + t + 1)) * 256;
                #pragma unroll
                for (int kf = 0; kf < 4; kf++) bn[kf] = cbt[tb + kf * 64 + lane];
            }
            facc4 acc[4];
            #pragma unroll
            for (int rt = 0; rt < 4; rt++) acc[rt] = (facc4){0.f, 0.f, 0.f, 0.f};
            #pragma unroll
            for (int kf = 0; kf < 4; kf++)
                #pragma unroll
                for (int rt = 0; rt < 4; rt++)
                    acc[rt] = __builtin_amdgcn_mfma_f32_16x16x32_bf16(af[rt][kf], bf[kf], acc[rt], 0, 0, 0);
            float wv = wsqs[cbase + t * 16 + r];
            #pragma unroll
            for (int rt = 0; rt < 4; rt++)
                #pragma unroll
                for (int i = 0; i < 4; i++)
                    rmin[rt * 4 + i] = fminf(rmin[rt * 4 + i], fmaf(-2.f, acc[rt][i], wv));
            // interleaved one-hot zero-fill (fire-and-forget)
            int j0 = t * 2;
            *(float4*)(enc + zb + (size_t)(j0 * TPB + tid) * 4) = z4;
            *(float4*)(enc + zb + (size_t)((j0 + 1) * TPB + tid) * 4) = z4;
            if (t + 1 < NTILE) {
                #pragma unroll
                for (int kf = 0; kf < 4; kf++) bf[kf] = bn[kf];
            }
        }
    }

    // ---- row thresholds: reduce over r-lanes, then over 8 waves
    #pragma unroll
    for (int t = 0; t < 16; t++) {
        float v = rmin[t];
        v = fminf(v, __shfl_xor(v, 1, 64));
        v = fminf(v, __shfl_xor(v, 2, 64));
        v = fminf(v, __shfl_xor(v, 4, 64));
        v = fminf(v, __shfl_xor(v, 8, 64));
        if (r == 0) redvw[w][(t >> 2) * 16 + q * 4 + (t & 3)] = v;
    }
    __syncthreads();
    if (tid < BM) {
        float mv = redvw[0][tid];
        #pragma unroll
        for (int i = 1; i < 8; i++) mv = fminf(mv, redvw[i][tid]);
        rowthr[tid] = mv + DELTA;
    }
    __syncthreads();

    float thr[16];
    #pragma unroll
    for (int t = 0; t < 16; t++) thr[t] = rowthr[(t >> 2) * 16 + q * 4 + (t & 3)];

    // ===== SWEEP 2: bitwise-identical recompute, collect candidates =========
    {
        bhalf8 bf[4];
        #pragma unroll
        for (int kf = 0; kf < 4; kf++)
            bf[kf] = cbt[((size_t)(cbase >> 4)) * 256 + kf * 64 + lane];
        #pragma unroll
        for (int t = 0; t < NTILE; t++) {
            bhalf8 bn[4];
            if (t + 1 < NTILE) {
                size_t tb = ((size_t)((cbase >> 4) + t + 1)) * 256;
                #pragma unroll
                for (int kf = 0; kf < 4; kf++) bn[kf] = cbt[tb + kf * 64 + lane];
            }
            facc4 acc[4];
            #pragma unroll
            for (int rt = 0; rt < 4; rt++) acc[rt] = (facc4){0.f, 0.f, 0.f, 0.f};
            #pragma unroll
            for (int kf = 0; kf < 4; kf++)
                #pragma unroll
                for (int rt = 0; rt < 4; rt++)
                    acc[rt] = __builtin_amdgcn_mfma_f32_16x16x32_bf16(af[rt][kf], bf[kf], acc[rt], 0, 0, 0);
            float wv = wsqs[cbase + t * 16 + r];
            #pragma unroll
            for (int rt = 0; rt < 4; rt++)
                #pragma unroll
                for (int i = 0; i < 4; i++) {
                    float d = fmaf(-2.f, acc[rt][i], wv);
                    if (d <= thr[rt * 4 + i]) {
                        int row = rt * 16 + q * 4 + i;
                        int p = atomicAdd(&cnt[row], 1);
                        if (p < CAP) candk[row][p] = cbase + t * 16 + r;
                    }
                }
            int j0 = 32 + t * 2;
            *(float4*)(enc + zb + (size_t)(j0 * TPB + tid) * 4) = z4;
            *(float4*)(enc + zb + (size_t)((j0 + 1) * TPB + tid) * 4) = z4;
            if (t + 1 < NTILE) {
                #pragma unroll
                for (int kf = 0; kf < 4; kf++) bf[kf] = bn[kf];
            }
        }
    }
    __syncthreads();

    // =============== SWEEP 3: exact fp32 rescore (8 rows per wave) ==========
    for (int m = 8 * w; m < 8 * w + 8; m++) {
        int c = min(cnt[m], CAP);
        float bv = 3.0e38f; int bk = 0x7fffffff;
        for (int t = 0; t < c; t++) {
            int k = candk[m][t];
            float x0 = As[lane][m], x1 = As[lane + 64][m];
            float c0 = cb[(size_t)k * CDIM + lane];
            float c1 = cb[(size_t)k * CDIM + 64 + lane];
            float s = x0 * c0 + x1 * c1;
            #pragma unroll
            for (int off = 1; off <= 32; off <<= 1) s += __shfl_xor(s, off, 64);
            float d = fmaf(-2.f, s, wsqs[k]);
            if (d < bv || (d == bv && k < bk)) { bv = d; bk = k; }
        }
        if (lane == 0) rowidx[m] = bk;
    }
    __syncthreads();

    // ---- the ones (zeros already drained by barrier's vmcnt(0))
    if (tid < BM) enc[(size_t)(n0 + tid) * KCODES + rowidx[tid]] = 1.0f;

    // ---- quantized = codebook[idx], NCHW coalesced float4 (folded)
    #pragma unroll
    for (int i = tid; i < BM * CDIM / 4; i += TPB) {
        int c  = i >> 4;
        int hq = (i & 15) << 2;
        float4 v;
        v.x = cb[(size_t)rowidx[hq + 0] * CDIM + c];
        v.y = cb[(size_t)rowidx[hq + 1] * CDIM + c];
        v.z = cb[(size_t)rowidx[hq + 2] * CDIM + c];
        v.w = cb[(size_t)rowidx[hq + 3] * CDIM + c];
        *(float4*)(quant + (((size_t)(b * CDIM + c)) << 10) + hw0 + hq) = v;
    }
}

extern "C" void kernel_launch(void* const* d_in, const int* in_sizes, int n_in,
                              void* d_out, int out_size, void* d_ws, size_t ws_size,
                              hipStream_t stream) {
    const float* x  = (const float*)d_in[0];   // [16,128,32,32] f32
    const float* cb = (const float*)d_in[1];   // [2048,128] f32
    float* out = (float*)d_out;                // encodings [N,K] then quantized

    bhalf8* cbt  = (bhalf8*)d_ws;                              // 512 KB tiled bf16
    float*  wsqp = (float*)((char*)d_ws + 512 * 1024);         // 8 KB

    prep_kernel<<<KCODES / 16, 256, 0, stream>>>(cb, cbt, wsqp);
    argmin_kernel<<<N_TOK / BM, TPB, 0, stream>>>(x, cb, cbt, wsqp,
                                                  out, out + (size_t)N_TOK * KCODES);
}

// Round 5
// 191.343 us; speedup vs baseline: 1.9137x; 1.0611x over previous
//
#include <hip/hip_runtime.h>
#include <hip/hip_bf16.h>

#define N_TOK  16384   // B*H*W
#define KCODES 2048
#define CDIM   128
#define BM     64
#define TPB    512     // 8 waves: 4 compute + 4 fill
#define NCW    4       // compute waves
#define CPW    (KCODES / NCW)   // 512 codes per compute wave
#define TPW    (CPW / 16)       // 32 tiles per compute wave
#define CAP    40
#define DELTA  5.0f    // bf16 d2 error bound ~1.05; 5 is ~5x safe (validated R4)
#define ASTR   68

typedef __attribute__((ext_vector_type(8))) short bhalf8;
typedef __attribute__((ext_vector_type(4))) float facc4;

// ---- prep: codebook fp32 -> bf16 in MFMA-frag-tiled layout, + ||w||^2 ----
// element (16B) index = T*256 + kf*64 + (q*16 + r)
//   holds code (T*16+r), dims [kf*32 + q*8, +8)  == B-frag for (tile T, kf)
__global__ __launch_bounds__(256) void prep_kernel(const float* __restrict__ cb,
                                                   bhalf8* __restrict__ cbt,
                                                   float* __restrict__ wsq) {
    const int T   = blockIdx.x;
    const int tid = threadIdx.x;
    const int r   = tid >> 4;
    const int g   = tid & 15;
    const float4* src = (const float4*)(cb + ((size_t)(T * 16 + r)) * CDIM + g * 8);
    float4 a0 = src[0], a1 = src[1];

    float s = a0.x*a0.x + a0.y*a0.y + a0.z*a0.z + a0.w*a0.w
            + a1.x*a1.x + a1.y*a1.y + a1.z*a1.z + a1.w*a1.w;
    s += __shfl_xor(s, 1, 64);
    s += __shfl_xor(s, 2, 64);
    s += __shfl_xor(s, 4, 64);
    s += __shfl_xor(s, 8, 64);
    if (g == 0) wsq[T * 16 + r] = s;

    union { unsigned u[4]; bhalf8 v; } fu;
    __hip_bfloat162 h0 = __float22bfloat162_rn(make_float2(a0.x, a0.y));
    __hip_bfloat162 h1 = __float22bfloat162_rn(make_float2(a0.z, a0.w));
    __hip_bfloat162 h2 = __float22bfloat162_rn(make_float2(a1.x, a1.y));
    __hip_bfloat162 h3 = __float22bfloat162_rn(make_float2(a1.z, a1.w));
    fu.u[0] = *(unsigned*)&h0; fu.u[1] = *(unsigned*)&h1;
    fu.u[2] = *(unsigned*)&h2; fu.u[3] = *(unsigned*)&h3;
    const int kf = g >> 2, q = g & 3;
    cbt[(size_t)T * 256 + kf * 64 + q * 16 + r] = fu.v;
}

// ---- main: wave-specialized (4 MFMA-sweep waves + 4 store-stream waves) ----
__global__ __launch_bounds__(TPB, 1) void argmin_kernel(const float* __restrict__ x,
                                                        const float* __restrict__ cb,
                                                        const bhalf8* __restrict__ cbt,
                                                        const float* __restrict__ wsqg,
                                                        float* __restrict__ enc,
                                                        float* __restrict__ quant) {
    __shared__ float As[CDIM][ASTR];     // 34.8 KB exact fp32 x, c-major
    __shared__ float wsqs[KCODES];       // 8 KB
    __shared__ float redvw[NCW][BM];
    __shared__ float rowthr[BM];
    __shared__ int   cnt[BM];
    __shared__ int   candk[BM][CAP];
    __shared__ int   rowidx[BM];

    const int tid  = threadIdx.x;
    const int lane = tid & 63;
    const int w    = tid >> 6;
    const int q    = lane >> 4;
    const int r    = lane & 15;
    const int n0   = blockIdx.x * BM;    // 1024 % 64 == 0: single batch
    const int b    = n0 >> 10;
    const int hw0  = n0 & 1023;
    const float4 z4 = {0.f, 0.f, 0.f, 0.f};

    // ---- stage As (coalesced float4 over hw), wsqs, init cnt
    {
        int m4 = (tid & 15) << 2;
        int c0 = tid >> 4;               // 0..31
        #pragma unroll
        for (int i = 0; i < 4; i++) {
            int c = c0 + 32 * i;
            float4 v = *(const float4*)(x + (((size_t)(b * CDIM + c)) << 10) + hw0 + m4);
            *(float4*)(&As[c][m4]) = v;
        }
    }
    #pragma unroll
    for (int i = 0; i < KCODES / TPB; i++) wsqs[i * TPB + tid] = wsqg[i * TPB + tid];
    if (tid < BM) cnt[tid] = 0;
    __syncthreads();

    // ---- compute waves: A-frags in registers (A[m=lane&15][k=q*8+j], verified R3/R4)
    bhalf8 af[4][4];
    if (w < NCW) {
        #pragma unroll
        for (int rt = 0; rt < 4; rt++) {
            int m = rt * 16 + r;
            #pragma unroll
            for (int kf = 0; kf < 4; kf++) {
                union { unsigned u[4]; bhalf8 v; } fu;
                #pragma unroll
                for (int p = 0; p < 4; p++) {
                    int k = kf * 32 + q * 8 + 2 * p;
                    __hip_bfloat162 h = __float22bfloat162_rn(make_float2(As[k][m], As[k + 1][m]));
                    fu.u[p] = *(unsigned*)&h;
                }
                af[rt][kf] = fu.v;
            }
        }
    }

    const int    cw  = w * CPW;                       // compute wave's code base
    const size_t tb0 = (size_t)(cw >> 4) * 256;       // its first tile's frag base

    // =============== phase 1: sweep 1 (compute) | fill half A (fill) ========
    if (w < NCW) {
        float rmin[16];
        #pragma unroll
        for (int t = 0; t < 16; t++) rmin[t] = 3.0e38f;

        bhalf8 bcur[4], bnxt[4];
        #pragma unroll
        for (int kf = 0; kf < 4; kf++) bcur[kf] = cbt[tb0 + kf * 64 + lane];
        #pragma unroll
        for (int kf = 0; kf < 4; kf++) bnxt[kf] = cbt[tb0 + 256 + kf * 64 + lane];

        for (int t = 0; t < TPW; t++) {
            bhalf8 bn2[4];
            if (t + 2 < TPW) {
                size_t tb = tb0 + (size_t)(t + 2) * 256;
                #pragma unroll
                for (int kf = 0; kf < 4; kf++) bn2[kf] = cbt[tb + kf * 64 + lane];
            }
            facc4 acc[4];
            #pragma unroll
            for (int rt = 0; rt < 4; rt++) acc[rt] = (facc4){0.f, 0.f, 0.f, 0.f};
            #pragma unroll
            for (int kf = 0; kf < 4; kf++)
                #pragma unroll
                for (int rt = 0; rt < 4; rt++)
                    acc[rt] = __builtin_amdgcn_mfma_f32_16x16x32_bf16(af[rt][kf], bcur[kf], acc[rt], 0, 0, 0);
            float wv = wsqs[cw + t * 16 + r];
            #pragma unroll
            for (int rt = 0; rt < 4; rt++)
                #pragma unroll
                for (int i = 0; i < 4; i++)
                    rmin[rt * 4 + i] = fminf(rmin[rt * 4 + i], fmaf(-2.f, acc[rt][i], wv));
            #pragma unroll
            for (int kf = 0; kf < 4; kf++) { bcur[kf] = bnxt[kf]; bnxt[kf] = bn2[kf]; }
        }
        #pragma unroll
        for (int t = 0; t < 16; t++) {
            float v = rmin[t];
            v = fminf(v, __shfl_xor(v, 1, 64));
            v = fminf(v, __shfl_xor(v, 2, 64));
            v = fminf(v, __shfl_xor(v, 4, 64));
            v = fminf(v, __shfl_xor(v, 8, 64));
            if (r == 0) redvw[w][(t >> 2) * 16 + q * 4 + (t & 3)] = v;
        }
    } else {
        // fill wave f: rows [f*16, f*16+16); first 8 rows now (64 x 1KB stores)
        const int f = w - NCW;
        float4* dst = (float4*)(enc + (size_t)(n0 + f * 16) * KCODES);
        #pragma unroll 8
        for (int i = 0; i < 64; i++) dst[(size_t)i * 64 + lane] = z4;
    }
    __syncthreads();
    if (tid < BM) {
        float mv = fminf(fminf(redvw[0][tid], redvw[1][tid]),
                         fminf(redvw[2][tid], redvw[3][tid]));
        rowthr[tid] = mv + DELTA;
    }
    __syncthreads();

    // =============== phase 2: sweep 2 (compute) | fill half B (fill) ========
    if (w < NCW) {
        float thr[16];
        #pragma unroll
        for (int t = 0; t < 16; t++) thr[t] = rowthr[(t >> 2) * 16 + q * 4 + (t & 3)];

        bhalf8 bcur[4], bnxt[4];
        #pragma unroll
        for (int kf = 0; kf < 4; kf++) bcur[kf] = cbt[tb0 + kf * 64 + lane];
        #pragma unroll
        for (int kf = 0; kf < 4; kf++) bnxt[kf] = cbt[tb0 + 256 + kf * 64 + lane];

        for (int t = 0; t < TPW; t++) {
            bhalf8 bn2[4];
            if (t + 2 < TPW) {
                size_t tb = tb0 + (size_t)(t + 2) * 256;
                #pragma unroll
                for (int kf = 0; kf < 4; kf++) bn2[kf] = cbt[tb + kf * 64 + lane];
            }
            facc4 acc[4];
            #pragma unroll
            for (int rt = 0; rt < 4; rt++) acc[rt] = (facc4){0.f, 0.f, 0.f, 0.f};
            #pragma unroll
            for (int kf = 0; kf < 4; kf++)
                #pragma unroll
                for (int rt = 0; rt < 4; rt++)
                    acc[rt] = __builtin_amdgcn_mfma_f32_16x16x32_bf16(af[rt][kf], bcur[kf], acc[rt], 0, 0, 0);
            float wv = wsqs[cw + t * 16 + r];
            #pragma unroll
            for (int rt = 0; rt < 4; rt++)
                #pragma unroll
                for (int i = 0; i < 4; i++) {
                    float d = fmaf(-2.f, acc[rt][i], wv);
                    if (d <= thr[rt * 4 + i]) {
                        int row = rt * 16 + q * 4 + i;
                        int p = atomicAdd(&cnt[row], 1);
                        if (p < CAP) candk[row][p] = cw + t * 16 + r;
                    }
                }
            #pragma unroll
            for (int kf = 0; kf < 4; kf++) { bcur[kf] = bnxt[kf]; bnxt[kf] = bn2[kf]; }
        }
    } else {
        const int f = w - NCW;
        float4* dst = (float4*)(enc + (size_t)(n0 + f * 16) * KCODES);
        #pragma unroll 8
        for (int i = 64; i < 128; i++) dst[(size_t)i * 64 + lane] = z4;
    }
    __syncthreads();

    // =============== sweep 3: exact fp32 rescore (all 8 waves, 8 rows each) =
    for (int m = 8 * w; m < 8 * w + 8; m++) {
        int c = min(cnt[m], CAP);
        float bv = 3.0e38f; int bk = 0x7fffffff;
        for (int t = 0; t < c; t++) {
            int k = candk[m][t];
            float x0 = As[lane][m], x1 = As[lane + 64][m];
            float c0 = cb[(size_t)k * CDIM + lane];
            float c1 = cb[(size_t)k * CDIM + 64 + lane];
            float s = x0 * c0 + x1 * c1;
            #pragma unroll
            for (int off = 1; off <= 32; off <<= 1) s += __shfl_xor(s, off, 64);
            float d = fmaf(-2.f, s, wsqs[k]);
            if (d < bv || (d == bv && k < bk)) { bv = d; bk = k; }
        }
        if (lane == 0) rowidx[m] = bk;
    }
    __syncthreads();

    // ---- ones (zeros drained by barrier) + quantized NCHW (folded)
    if (tid < BM) enc[(size_t)(n0 + tid) * KCODES + rowidx[tid]] = 1.0f;

    #pragma unroll
    for (int i = tid; i < BM * CDIM / 4; i += TPB) {
        int c  = i >> 4;
        int hq = (i & 15) << 2;
        float4 v;
        v.x = cb[(size_t)rowidx[hq + 0] * CDIM + c];
        v.y = cb[(size_t)rowidx[hq + 1] * CDIM + c];
        v.z = cb[(size_t)rowidx[hq + 2] * CDIM + c];
        v.w = cb[(size_t)rowidx[hq + 3] * CDIM + c];
        *(float4*)(quant + (((size_t)(b * CDIM + c)) << 10) + hw0 + hq) = v;
    }
}

extern "C" void kernel_launch(void* const* d_in, const int* in_sizes, int n_in,
                              void* d_out, int out_size, void* d_ws, size_t ws_size,
                              hipStream_t stream) {
    const float* x  = (const float*)d_in[0];   // [16,128,32,32] f32
    const float* cb = (const float*)d_in[1];   // [2048,128] f32
    float* out = (float*)d_out;                // encodings [N,K] then quantized

    bhalf8* cbt  = (bhalf8*)d_ws;                      // 512 KB tiled bf16
    float*  wsqp = (float*)((char*)d_ws + 512 * 1024); // 8 KB

    prep_kernel<<<KCODES / 16, 256, 0, stream>>>(cb, cbt, wsqp);
    argmin_kernel<<<N_TOK / BM, TPB, 0, stream>>>(x, cb, cbt, wsqp,
                                                  out, out + (size_t)N_TOK * KCODES);
}